// Round 4
// baseline (193.228 us; speedup 1.0000x reference)
//
#include <hip/hip_runtime.h>

// GCN layer: out = Ahat @ x @ W^T + bias, Ahat = D^-1/2 (A + I) D^-1/2
// Pipeline: k_prep (zero gcnt, W->bf16 once) -> k_bin: bucket binning
// (dst>>8, LDS counting sort, contiguous run writes; 2048-edge chunks for
// 2x block parallelism) -> k_cnt: per-bucket LDS histogram => dinv ->
// k_gemm: y' = dinv*(x@W^T), LDS-free / barrier-free (direct global A
// fragments, pre-converted bf16 W) -> k_aggr (FUSED, proven 53.7us): LDS
// counting-sort by dst&255 + per-dest gather + epilogue.
// R4: attack the invisible-middle latency chains; k_aggr untouched.

#define NBMAX 400
#define CAP   5120   // bucket capacity: mean 4096 + 16 sigma (sigma ~ 64)
#define CHUNK 2048   // k_bin edges per block

typedef short bf16x8 __attribute__((ext_vector_type(8)));
typedef float f32x4  __attribute__((ext_vector_type(4)));

__device__ inline float bflo(unsigned u) { return __uint_as_float(u << 16); }
__device__ inline float bfhi(unsigned u) { return __uint_as_float(u & 0xFFFF0000u); }
__device__ inline unsigned short f2bf(float f) {           // round-nearest-even
    unsigned u = __float_as_uint(f);
    u += 0x7FFFu + ((u >> 16) & 1u);
    return (unsigned short)(u >> 16);
}

__device__ inline bf16x8 cvt8(float4 a, float4 b) {        // 8 f32 -> bf16x8
    bf16x8 r;
    r[0] = (short)f2bf(a.x); r[1] = (short)f2bf(a.y);
    r[2] = (short)f2bf(a.z); r[3] = (short)f2bf(a.w);
    r[4] = (short)f2bf(b.x); r[5] = (short)f2bf(b.y);
    r[6] = (short)f2bf(b.z); r[7] = (short)f2bf(b.w);
    return r;
}

// Zero gcnt; convert W (64x64 f32) to bf16 once.
__global__ __launch_bounds__(256) void k_prep(const float* __restrict__ W,
                                              unsigned short* __restrict__ wbf,
                                              int* __restrict__ gcnt, int NB) {
    int gid = blockIdx.x * 256 + threadIdx.x;
    if (gid < 4096) wbf[gid] = f2bf(W[gid]);
    if (gid < NB) gcnt[gid] = 0;
}

// Chunk-local LDS counting sort by bucket (dst>>8); contiguous run copy-out of
// packed (src | (dst&255)<<24) records into fixed-stride bucket regions.
// gcnt[b] counts records in bucket b; region base = b*CAP.
__global__ __launch_bounds__(256) void k_bin(const int* __restrict__ row,
                                             const int* __restrict__ col,
                                             int* __restrict__ gcnt,
                                             unsigned int* __restrict__ ebuf, int E) {
    __shared__ unsigned int   sorted4[CHUNK];  // 8 KB packed records
    __shared__ unsigned short sbkt[CHUNK];     // 4 KB bucket id per slot
    __shared__ int h[NBMAX], hstart[NBMAX], hcur[NBMAX], gof[NBMAX];
    int t = threadIdx.x;
    int base = blockIdx.x * CHUNK;
    int total = min(CHUNK, E - base);

    int rr[8], cc[8];
    #pragma unroll
    for (int i = 0; i < 2; ++i) {
        int e0 = (t + i * 256) * 4;
        if (e0 + 3 < total) {
            int4 r4 = *(const int4*)(row + base + e0);
            int4 c4 = *(const int4*)(col + base + e0);
            rr[i*4+0]=r4.x; rr[i*4+1]=r4.y; rr[i*4+2]=r4.z; rr[i*4+3]=r4.w;
            cc[i*4+0]=c4.x; cc[i*4+1]=c4.y; cc[i*4+2]=c4.z; cc[i*4+3]=c4.w;
        } else {
            #pragma unroll
            for (int j = 0; j < 4; ++j) {
                int e = e0 + j;
                if (e < total) { rr[i*4+j] = row[base+e]; cc[i*4+j] = col[base+e]; }
                else cc[i*4+j] = -1;
            }
        }
    }
    for (int b = t; b < NBMAX; b += 256) h[b] = 0;
    __syncthreads();
    #pragma unroll
    for (int i = 0; i < 8; ++i)
        if (cc[i] >= 0) atomicAdd(&h[cc[i] >> 8], 1);
    __syncthreads();
    if (t < 64) {                              // wave-0 scan of h
        int lo = t * 7;
        int loc[7]; int s = 0;
        #pragma unroll
        for (int i = 0; i < 7; ++i) {
            loc[i] = s;
            int idx = lo + i;
            s += (idx < NBMAX) ? h[idx] : 0;
        }
        int incl = s;
        for (int off = 1; off < 64; off <<= 1) {
            int v = __shfl_up(incl, off);
            if (t >= off) incl += v;
        }
        int ex = incl - s;
        #pragma unroll
        for (int i = 0; i < 7; ++i) {
            int idx = lo + i;
            if (idx < NBMAX) hstart[idx] = ex + loc[i];
        }
    }
    __syncthreads();
    for (int b = t; b < NBMAX; b += 256) hcur[b] = hstart[b];
    __syncthreads();
    #pragma unroll
    for (int i = 0; i < 8; ++i) {
        if (cc[i] >= 0) {
            int b = cc[i] >> 8;
            int rank = atomicAdd(&hcur[b], 1);
            sorted4[rank] = (unsigned)rr[i] | ((unsigned)(cc[i] & 255) << 24);
            sbkt[rank] = (unsigned short)b;
        }
    }
    for (int b = t; b < NBMAX; b += 256) {
        int m = h[b];
        gof[b] = b * CAP + (m ? atomicAdd(&gcnt[b], m) : 0);
    }
    __syncthreads();
    for (int i = t; i < total; i += 256) {     // contiguous per-bucket runs
        int b = sbkt[i];
        ebuf[gof[b] + (i - hstart[b])] = sorted4[i];
    }
}

// Per-bucket degree histogram -> dinv. Coalesced read, LDS atomics only.
__global__ __launch_bounds__(256) void k_cnt(const unsigned int* __restrict__ ebuf,
                                             const int* __restrict__ gcnt,
                                             float* __restrict__ dinv, int n) {
    __shared__ int h[256];
    int b = blockIdx.x, t = threadIdx.x;
    int s0 = b * CAP;
    int count = min(gcnt[b], CAP);
    h[t] = 0;
    __syncthreads();
    for (int i = t; i < count; i += 256) atomicAdd(&h[ebuf[s0 + i] >> 24], 1);
    __syncthreads();
    int c = b * 256 + t;
    if (c < n) dinv[c] = rsqrtf((float)(h[t] + 1));
}

// y' = dinv * (x @ W^T) via bf16 MFMA 16x16x32; 64 rows per block.
// LDS-free, barrier-free: A fragments load directly from global (each lane's
// fragment = 2x32 B of one x row; a wave covers a contiguous 4 KB block of x),
// B fragments read pre-converted bf16 W from L2. Direct scattered yb stores
// (R0-proven epilogue).
__global__ __launch_bounds__(256) void k_gemm(const float* __restrict__ x,
                                              const unsigned short* __restrict__ wbf,
                                              const float* __restrict__ dinv,
                                              unsigned short* __restrict__ yb, int n) {
    int t = threadIdx.x;
    int lane = t & 63, wid = t >> 6;
    int m = blockIdx.x * 64 + wid * 16 + (lane & 15);
    int kg = (lane >> 4) * 8;
    bf16x8 a0 = {0,0,0,0,0,0,0,0}, a1 = a0;
    if (m < n) {
        const float* xr = x + (long long)m * 64 + kg;
        float4 p0 = *(const float4*)(xr);
        float4 p1 = *(const float4*)(xr + 4);
        float4 p2 = *(const float4*)(xr + 32);
        float4 p3 = *(const float4*)(xr + 36);
        a0 = cvt8(p0, p1);
        a1 = cvt8(p2, p3);
    }
    int bn = lane & 15;
    f32x4 acc0 = {0.f,0.f,0.f,0.f}, acc1 = acc0, acc2 = acc0, acc3 = acc0;
    {
        bf16x8 b0 = *(const bf16x8*)(wbf + (bn     ) * 64 + kg);
        bf16x8 b1 = *(const bf16x8*)(wbf + (bn     ) * 64 + 32 + kg);
        acc0 = __builtin_amdgcn_mfma_f32_16x16x32_bf16(a0, b0, acc0, 0, 0, 0);
        acc0 = __builtin_amdgcn_mfma_f32_16x16x32_bf16(a1, b1, acc0, 0, 0, 0);
    }
    {
        bf16x8 b0 = *(const bf16x8*)(wbf + (bn + 16) * 64 + kg);
        bf16x8 b1 = *(const bf16x8*)(wbf + (bn + 16) * 64 + 32 + kg);
        acc1 = __builtin_amdgcn_mfma_f32_16x16x32_bf16(a0, b0, acc1, 0, 0, 0);
        acc1 = __builtin_amdgcn_mfma_f32_16x16x32_bf16(a1, b1, acc1, 0, 0, 0);
    }
    {
        bf16x8 b0 = *(const bf16x8*)(wbf + (bn + 32) * 64 + kg);
        bf16x8 b1 = *(const bf16x8*)(wbf + (bn + 32) * 64 + 32 + kg);
        acc2 = __builtin_amdgcn_mfma_f32_16x16x32_bf16(a0, b0, acc2, 0, 0, 0);
        acc2 = __builtin_amdgcn_mfma_f32_16x16x32_bf16(a1, b1, acc2, 0, 0, 0);
    }
    {
        bf16x8 b0 = *(const bf16x8*)(wbf + (bn + 48) * 64 + kg);
        bf16x8 b1 = *(const bf16x8*)(wbf + (bn + 48) * 64 + 32 + kg);
        acc3 = __builtin_amdgcn_mfma_f32_16x16x32_bf16(a0, b0, acc3, 0, 0, 0);
        acc3 = __builtin_amdgcn_mfma_f32_16x16x32_bf16(a1, b1, acc3, 0, 0, 0);
    }
    // C/D layout: col = lane&15, row = (lane>>4)*4 + reg  [m89-verified]
    int rbase = blockIdx.x * 64 + wid * 16 + (lane >> 4) * 4;
    #pragma unroll
    for (int i = 0; i < 4; ++i) {
        int r = rbase + i;
        if (r < n) {
            float dv = dinv[r];
            long long ro = (long long)r * 64 + bn;
            yb[ro +  0] = f2bf(dv * acc0[i]);
            yb[ro + 16] = f2bf(dv * acc1[i]);
            yb[ro + 32] = f2bf(dv * acc2[i]);
            yb[ro + 48] = f2bf(dv * acc3[i]);
        }
    }
}

// FUSED sort+gather: one 1024-thread block per bucket. LDS counting sort by
// dst&255 (sbuf never leaves LDS); then each 16-lane group gathers one dest's
// src list (broadcast ds_read) and writes out directly.
__global__ __launch_bounds__(1024) void k_aggr(const unsigned int* __restrict__ ebuf,
                                               const int* __restrict__ gcnt,
                                               const float* __restrict__ dinv,
                                               const unsigned short* __restrict__ yb,
                                               const float* __restrict__ bias,
                                               float* __restrict__ out, int n) {
    __shared__ int h[256], hstart[256], hc[256], wsum[4];
    __shared__ int sbuf[CAP];                  // 20 KB, LDS-only
    int b = blockIdx.x, t = threadIdx.x;
    int s0 = b * CAP;
    int count = min(gcnt[b], CAP);

    if (t < 256) h[t] = 0;
    __syncthreads();
    unsigned rec[5];
    #pragma unroll
    for (int k = 0; k < 5; ++k) {              // coalesced load + LDS hist
        int i = t + k * 1024;
        if (i < count) {
            unsigned p = ebuf[s0 + i];
            rec[k] = p;
            atomicAdd(&h[p >> 24], 1);
        }
    }
    __syncthreads();
    if (t < 256) {                             // wave-shfl inclusive scan
        int v = h[t];
        int lane = t & 63, wid = t >> 6;
        int incl = v;
        #pragma unroll
        for (int off = 1; off < 64; off <<= 1) {
            int u = __shfl_up(incl, off);
            if (lane >= off) incl += u;
        }
        hstart[t] = incl;                      // temp: inclusive
        if (lane == 63) wsum[wid] = incl;
    }
    __syncthreads();
    if (t < 256) {
        int wid = t >> 6;
        int add = 0;
        for (int w = 0; w < wid; ++w) add += wsum[w];
        int ex = hstart[t] - h[t] + add;       // exclusive prefix
        hstart[t] = ex;
        hc[t] = ex;
    }
    __syncthreads();
    #pragma unroll
    for (int k = 0; k < 5; ++k) {              // counting-sort scatter (LDS)
        int i = t + k * 1024;
        if (i < count) {
            unsigned p = rec[k];
            int r = atomicAdd(&hc[p >> 24], 1);
            sbuf[r] = (int)(p & 0x1FFFFu);
        }
    }
    __syncthreads();

    // Gather: 16 waves x 4 groups = 64 dest-slots; 4 rounds cover 256 dests.
    int lane = t & 63, w = t >> 6;
    int g = lane >> 4, q = lane & 15;
    #pragma unroll
    for (int r = 0; r < 4; ++r) {
        int cl = r * 64 + w * 4 + g;
        int c = b * 256 + cl;
        if (c >= n) continue;                  // no barriers below: safe
        int start = hstart[cl], len = h[cl];
        float a0 = 0.f, a1 = 0.f, a2 = 0.f, a3 = 0.f;
        if (len > 0) {
            int sc = sbuf[start];              // prefetched src
            for (int i = 0; i < len; ++i) {
                int sn = (i + 1 < len) ? sbuf[start + i + 1] : 0;
                float2 v = *(const float2*)(yb + (long long)sc * 64 + (q << 2));
                unsigned u0 = __float_as_uint(v.x), u1 = __float_as_uint(v.y);
                a0 += bflo(u0); a1 += bfhi(u0);
                a2 += bflo(u1); a3 += bfhi(u1);
                sc = sn;
            }
        }
        {   // self loop
            float2 v = *(const float2*)(yb + (long long)c * 64 + (q << 2));
            unsigned u0 = __float_as_uint(v.x), u1 = __float_as_uint(v.y);
            a0 += bflo(u0); a1 += bfhi(u0);
            a2 += bflo(u1); a3 += bfhi(u1);
        }
        float dc = dinv[c];
        float4 bv = *(const float4*)(bias + (q << 2));
        *(float4*)(out + (long long)c * 64 + (q << 2)) =
            make_float4(dc * a0 + bv.x, dc * a1 + bv.y,
                        dc * a2 + bv.z, dc * a3 + bv.w);
    }
}

extern "C" void kernel_launch(void* const* d_in, const int* in_sizes, int n_in,
                              void* d_out, int out_size, void* d_ws, size_t ws_size,
                              hipStream_t stream) {
    const float* x    = (const float*)d_in[0];
    const int*   ei   = (const int*)d_in[1];
    // d_in[2] = x0 (unused: use_init=False)
    const float* W    = (const float*)d_in[3];
    const float* bias = (const float*)d_in[4];
    float* out = (float*)d_out;

    int n = in_sizes[0] / 64;
    int E = in_sizes[1] / 2;
    const int* row = ei;        // source
    const int* col = ei + E;    // target

    int NB = (n + 255) / 256;   // 391 (<= NBMAX, <= 512)

    char* ws = (char*)d_ws;
    size_t off = 0;
    auto alloc = [&](size_t bytes) { char* p = ws + off; off += (bytes + 15) & ~size_t(15); return p; };
    int*            gcnt = (int*)  alloc((size_t)NB * 4);
    float*          dinv = (float*)alloc((size_t)n * 4);
    unsigned short* yb   = (unsigned short*)alloc((size_t)n * 64 * 2);
    unsigned int*   ebuf = (unsigned int*)alloc((size_t)NB * CAP * 4);
    unsigned short* wbf  = (unsigned short*)alloc((size_t)4096 * 2);

    int nbE = (E + CHUNK - 1) / CHUNK;

    k_prep<<<16, 256, 0, stream>>>(W, wbf, gcnt, NB);
    k_bin <<<nbE, 256, 0, stream>>>(row, col, gcnt, ebuf, E);
    k_cnt <<<NB, 256, 0, stream>>>(ebuf, gcnt, dinv, n);
    k_gemm<<<(n + 63) / 64, 256, 0, stream>>>(x, wbf, dinv, yb, n);
    k_aggr<<<NB, 1024, 0, stream>>>(ebuf, gcnt, dinv, yb, bias, out, n);
}

// Round 5
// 182.826 us; speedup vs baseline: 1.0569x; 1.0569x over previous
//
#include <hip/hip_runtime.h>

// GCN layer: out = Ahat @ x @ W^T + bias, Ahat = D^-1/2 (A + I) D^-1/2
// Pipeline: memset(gcnt) -> K1 FUSED [bin || gemm] (data-independent: bin
// consumes edges, gemm consumes x/W; blocks 0..nbBin-1 bin, rest gemm) ->
// k_cnt: per-bucket LDS histogram => dinv -> k_aggr (FUSED sort+gather):
// LDS counting-sort by dst&255 + per-dest gather with per-edge dinv[src]
// FMA (dinv is 400KB, L2-resident broadcast) + epilogue.
// R5: un-serialize the middle. gemm no longer needs dinv (moved into the
// gather as an FMA - zero extra VALU); bin and gemm share one launch so
// bin's barrier-latency chains hide under gemm's MFMA/load throughput.
// k_bin/k_gemm bodies are the R0-proven forms (CHUNK=4096, LDS-tile gemm).

#define NBMAX 400
#define CAP   5120   // bucket capacity: mean 4096 + 16 sigma (sigma ~ 64)

typedef short bf16x8 __attribute__((ext_vector_type(8)));
typedef float f32x4  __attribute__((ext_vector_type(4)));

__device__ inline float bflo(unsigned u) { return __uint_as_float(u << 16); }
__device__ inline float bfhi(unsigned u) { return __uint_as_float(u & 0xFFFF0000u); }
__device__ inline unsigned short f2bf(float f) {           // round-nearest-even
    unsigned u = __float_as_uint(f);
    u += 0x7FFFu + ((u >> 16) & 1u);
    return (unsigned short)(u >> 16);
}

// ---------------------------------------------------------------------------
// K1: fused [bin || gemm]. Shared LDS overlay:
//   bin : sorted4[4096]u32 (16384) | sbkt[4096]u16 (8192) | h/hstart/hcur/gof
//         [NBMAX]i32 (4*1600)  -> 30976 B
//   gemm: xs[64][72]u16 (9216) | Wb[64][72]u16 (9216)     -> 18432 B
// ---------------------------------------------------------------------------
__global__ __launch_bounds__(256) void k_fused(const int* __restrict__ row,
                                               const int* __restrict__ col,
                                               int* __restrict__ gcnt,
                                               unsigned int* __restrict__ ebuf, int E,
                                               const float* __restrict__ x,
                                               const float* __restrict__ W,
                                               unsigned short* __restrict__ yb, int n,
                                               int nbBin) {
    __shared__ __align__(16) char smem[30976];
    int t = threadIdx.x;

    if ((int)blockIdx.x < nbBin) {
        // ----------------- bin path (R0 k_bin, 4096-edge chunks) -----------
        unsigned int*   sorted4 = (unsigned int*)smem;
        unsigned short* sbkt    = (unsigned short*)(smem + 16384);
        int* h      = (int*)(smem + 24576);
        int* hstart = (int*)(smem + 26176);
        int* hcur   = (int*)(smem + 27776);
        int* gof    = (int*)(smem + 29376);
        int base = blockIdx.x * 4096;
        int total = min(4096, E - base);

        int rr[16], cc[16];
        #pragma unroll
        for (int i = 0; i < 4; ++i) {
            int e0 = (t + i * 256) * 4;
            if (e0 + 3 < total) {
                int4 r4 = *(const int4*)(row + base + e0);
                int4 c4 = *(const int4*)(col + base + e0);
                rr[i*4+0]=r4.x; rr[i*4+1]=r4.y; rr[i*4+2]=r4.z; rr[i*4+3]=r4.w;
                cc[i*4+0]=c4.x; cc[i*4+1]=c4.y; cc[i*4+2]=c4.z; cc[i*4+3]=c4.w;
            } else {
                #pragma unroll
                for (int j = 0; j < 4; ++j) {
                    int e = e0 + j;
                    if (e < total) { rr[i*4+j] = row[base+e]; cc[i*4+j] = col[base+e]; }
                    else cc[i*4+j] = -1;
                }
            }
        }
        for (int b = t; b < NBMAX; b += 256) h[b] = 0;
        __syncthreads();
        #pragma unroll
        for (int i = 0; i < 16; ++i)
            if (cc[i] >= 0) atomicAdd(&h[cc[i] >> 8], 1);
        __syncthreads();
        if (t < 64) {                              // wave-0 scan of h
            int lo = t * 7;
            int loc[7]; int s = 0;
            #pragma unroll
            for (int i = 0; i < 7; ++i) {
                loc[i] = s;
                int idx = lo + i;
                s += (idx < NBMAX) ? h[idx] : 0;
            }
            int incl = s;
            for (int off = 1; off < 64; off <<= 1) {
                int v = __shfl_up(incl, off);
                if (t >= off) incl += v;
            }
            int ex = incl - s;
            #pragma unroll
            for (int i = 0; i < 7; ++i) {
                int idx = lo + i;
                if (idx < NBMAX) hstart[idx] = ex + loc[i];
            }
        }
        __syncthreads();
        for (int b = t; b < NBMAX; b += 256) hcur[b] = hstart[b];
        __syncthreads();
        #pragma unroll
        for (int i = 0; i < 16; ++i) {
            if (cc[i] >= 0) {
                int b = cc[i] >> 8;
                int rank = atomicAdd(&hcur[b], 1);
                sorted4[rank] = (unsigned)rr[i] | ((unsigned)(cc[i] & 255) << 24);
                sbkt[rank] = (unsigned short)b;
            }
        }
        for (int b = t; b < NBMAX; b += 256) {
            int m = h[b];
            gof[b] = b * CAP + (m ? atomicAdd(&gcnt[b], m) : 0);
        }
        __syncthreads();
        for (int i = t; i < total; i += 256) {     // contiguous per-bucket runs
            int b = sbkt[i];
            ebuf[gof[b] + (i - hstart[b])] = sorted4[i];
        }
    } else {
        // ----------------- gemm path (R0 k_gemm, no dinv scaling) ----------
        unsigned short (*xs)[72] = (unsigned short (*)[72])smem;
        unsigned short (*Wb)[72] = (unsigned short (*)[72])(smem + 9216);
        int gb = blockIdx.x - nbBin;
        long long total = (long long)n * 64;
        long long xbase = (long long)gb * 4096;
        #pragma unroll
        for (int i = 0; i < 4; ++i) {
            int idx = t + i * 256;                 // float4 index 0..1023
            int r = idx >> 4, c4 = (idx & 15) << 2;
            long long g = xbase + (long long)idx * 4;
            float4 v;
            if (g + 3 < total) v = *(const float4*)(x + g);
            else {
                v.x = (g + 0 < total) ? x[g + 0] : 0.f;
                v.y = (g + 1 < total) ? x[g + 1] : 0.f;
                v.z = (g + 2 < total) ? x[g + 2] : 0.f;
                v.w = (g + 3 < total) ? x[g + 3] : 0.f;
            }
            ushort4 o; o.x = f2bf(v.x); o.y = f2bf(v.y); o.z = f2bf(v.z); o.w = f2bf(v.w);
            *(ushort4*)&xs[r][c4] = o;
            float4 wv = *(const float4*)(W + idx * 4);     // W: 4096 floats
            ushort4 wo; wo.x = f2bf(wv.x); wo.y = f2bf(wv.y); wo.z = f2bf(wv.z); wo.w = f2bf(wv.w);
            *(ushort4*)&Wb[r][c4] = wo;
        }
        __syncthreads();
        int lane = t & 63, wid = t >> 6;
        int m  = wid * 16 + (lane & 15);
        int kg = (lane >> 4) * 8;
        bf16x8 a0 = *(bf16x8*)&xs[m][kg];
        bf16x8 a1 = *(bf16x8*)&xs[m][32 + kg];
        int bn = lane & 15;
        f32x4 acc0 = {0.f,0.f,0.f,0.f}, acc1 = acc0, acc2 = acc0, acc3 = acc0;
        {
            bf16x8 b0 = *(bf16x8*)&Wb[bn][kg], b1 = *(bf16x8*)&Wb[bn][32 + kg];
            acc0 = __builtin_amdgcn_mfma_f32_16x16x32_bf16(a0, b0, acc0, 0, 0, 0);
            acc0 = __builtin_amdgcn_mfma_f32_16x16x32_bf16(a1, b1, acc0, 0, 0, 0);
        }
        {
            bf16x8 b0 = *(bf16x8*)&Wb[bn + 16][kg], b1 = *(bf16x8*)&Wb[bn + 16][32 + kg];
            acc1 = __builtin_amdgcn_mfma_f32_16x16x32_bf16(a0, b0, acc1, 0, 0, 0);
            acc1 = __builtin_amdgcn_mfma_f32_16x16x32_bf16(a1, b1, acc1, 0, 0, 0);
        }
        {
            bf16x8 b0 = *(bf16x8*)&Wb[bn + 32][kg], b1 = *(bf16x8*)&Wb[bn + 32][32 + kg];
            acc2 = __builtin_amdgcn_mfma_f32_16x16x32_bf16(a0, b0, acc2, 0, 0, 0);
            acc2 = __builtin_amdgcn_mfma_f32_16x16x32_bf16(a1, b1, acc2, 0, 0, 0);
        }
        {
            bf16x8 b0 = *(bf16x8*)&Wb[bn + 48][kg], b1 = *(bf16x8*)&Wb[bn + 48][32 + kg];
            acc3 = __builtin_amdgcn_mfma_f32_16x16x32_bf16(a0, b0, acc3, 0, 0, 0);
            acc3 = __builtin_amdgcn_mfma_f32_16x16x32_bf16(a1, b1, acc3, 0, 0, 0);
        }
        // C/D layout: col = lane&15, row = (lane>>4)*4 + reg  [m89-verified]
        int rbase = gb * 64 + wid * 16 + (lane >> 4) * 4;
        #pragma unroll
        for (int i = 0; i < 4; ++i) {
            int r = rbase + i;
            if (r < n) {
                long long ro = (long long)r * 64 + bn;
                yb[ro +  0] = f2bf(acc0[i]);
                yb[ro + 16] = f2bf(acc1[i]);
                yb[ro + 32] = f2bf(acc2[i]);
                yb[ro + 48] = f2bf(acc3[i]);
            }
        }
    }
}

// Per-bucket degree histogram -> dinv. Coalesced read, LDS atomics only.
__global__ __launch_bounds__(256) void k_cnt(const unsigned int* __restrict__ ebuf,
                                             const int* __restrict__ gcnt,
                                             float* __restrict__ dinv, int n) {
    __shared__ int h[256];
    int b = blockIdx.x, t = threadIdx.x;
    int s0 = b * CAP;
    int count = min(gcnt[b], CAP);
    h[t] = 0;
    __syncthreads();
    for (int i = t; i < count; i += 256) atomicAdd(&h[ebuf[s0 + i] >> 24], 1);
    __syncthreads();
    int c = b * 256 + t;
    if (c < n) dinv[c] = rsqrtf((float)(h[t] + 1));
}

// FUSED sort+gather: one 1024-thread block per bucket. LDS counting sort by
// dst&255 (sbuf never leaves LDS); then each 16-lane group gathers one dest's
// src list. yb rows are UNSCALED z = x@W^T; the gather applies dinv[src] as
// an FMA (dinv: 400 KB, L2-resident, broadcast across the 16-lane group,
// prefetched one iteration ahead). Self-loop weighted by dinv[c].
__global__ __launch_bounds__(1024) void k_aggr(const unsigned int* __restrict__ ebuf,
                                               const int* __restrict__ gcnt,
                                               const float* __restrict__ dinv,
                                               const unsigned short* __restrict__ yb,
                                               const float* __restrict__ bias,
                                               float* __restrict__ out, int n) {
    __shared__ int h[256], hstart[256], hc[256], wsum[4];
    __shared__ int sbuf[CAP];                  // 20 KB, LDS-only
    int b = blockIdx.x, t = threadIdx.x;
    int s0 = b * CAP;
    int count = min(gcnt[b], CAP);

    if (t < 256) h[t] = 0;
    __syncthreads();
    unsigned rec[5];
    #pragma unroll
    for (int k = 0; k < 5; ++k) {              // coalesced load + LDS hist
        int i = t + k * 1024;
        if (i < count) {
            unsigned p = ebuf[s0 + i];
            rec[k] = p;
            atomicAdd(&h[p >> 24], 1);
        }
    }
    __syncthreads();
    if (t < 256) {                             // wave-shfl inclusive scan
        int v = h[t];
        int lane = t & 63, wid = t >> 6;
        int incl = v;
        #pragma unroll
        for (int off = 1; off < 64; off <<= 1) {
            int u = __shfl_up(incl, off);
            if (lane >= off) incl += u;
        }
        hstart[t] = incl;                      // temp: inclusive
        if (lane == 63) wsum[wid] = incl;
    }
    __syncthreads();
    if (t < 256) {
        int wid = t >> 6;
        int add = 0;
        for (int w = 0; w < wid; ++w) add += wsum[w];
        int ex = hstart[t] - h[t] + add;       // exclusive prefix
        hstart[t] = ex;
        hc[t] = ex;
    }
    __syncthreads();
    #pragma unroll
    for (int k = 0; k < 5; ++k) {              // counting-sort scatter (LDS)
        int i = t + k * 1024;
        if (i < count) {
            unsigned p = rec[k];
            int r = atomicAdd(&hc[p >> 24], 1);
            sbuf[r] = (int)(p & 0x1FFFFu);
        }
    }
    __syncthreads();

    // Gather: 16 waves x 4 groups = 64 dest-slots; 4 rounds cover 256 dests.
    int lane = t & 63, w = t >> 6;
    int g = lane >> 4, q = lane & 15;
    #pragma unroll
    for (int r = 0; r < 4; ++r) {
        int cl = r * 64 + w * 4 + g;
        int c = b * 256 + cl;
        if (c >= n) continue;                  // no barriers below: safe
        int start = hstart[cl], len = h[cl];
        float a0 = 0.f, a1 = 0.f, a2 = 0.f, a3 = 0.f;
        if (len > 0) {
            int sc = sbuf[start];              // prefetched src + its dinv
            float ds = dinv[sc];
            for (int i = 0; i < len; ++i) {
                int sn = (i + 1 < len) ? sbuf[start + i + 1] : 0;
                float dn = dinv[sn];
                float2 v = *(const float2*)(yb + (long long)sc * 64 + (q << 2));
                unsigned u0 = __float_as_uint(v.x), u1 = __float_as_uint(v.y);
                a0 += ds * bflo(u0); a1 += ds * bfhi(u0);
                a2 += ds * bflo(u1); a3 += ds * bfhi(u1);
                sc = sn; ds = dn;
            }
        }
        float dc = dinv[c];
        {   // self loop, weight dinv[c]
            float2 v = *(const float2*)(yb + (long long)c * 64 + (q << 2));
            unsigned u0 = __float_as_uint(v.x), u1 = __float_as_uint(v.y);
            a0 += dc * bflo(u0); a1 += dc * bfhi(u0);
            a2 += dc * bflo(u1); a3 += dc * bfhi(u1);
        }
        float4 bv = *(const float4*)(bias + (q << 2));
        *(float4*)(out + (long long)c * 64 + (q << 2)) =
            make_float4(dc * a0 + bv.x, dc * a1 + bv.y,
                        dc * a2 + bv.z, dc * a3 + bv.w);
    }
}

extern "C" void kernel_launch(void* const* d_in, const int* in_sizes, int n_in,
                              void* d_out, int out_size, void* d_ws, size_t ws_size,
                              hipStream_t stream) {
    const float* x    = (const float*)d_in[0];
    const int*   ei   = (const int*)d_in[1];
    // d_in[2] = x0 (unused: use_init=False)
    const float* W    = (const float*)d_in[3];
    const float* bias = (const float*)d_in[4];
    float* out = (float*)d_out;

    int n = in_sizes[0] / 64;
    int E = in_sizes[1] / 2;
    const int* row = ei;        // source
    const int* col = ei + E;    // target

    int NB = (n + 255) / 256;   // 391 (<= NBMAX, <= 512)

    char* ws = (char*)d_ws;
    size_t off = 0;
    auto alloc = [&](size_t bytes) { char* p = ws + off; off += (bytes + 15) & ~size_t(15); return p; };
    int*            gcnt = (int*)  alloc((size_t)NB * 4);
    float*          dinv = (float*)alloc((size_t)n * 4);
    unsigned short* yb   = (unsigned short*)alloc((size_t)n * 64 * 2);
    unsigned int*   ebuf = (unsigned int*)alloc((size_t)NB * CAP * 4);

    int nbBin  = (E + 4095) / 4096;            // 391
    int nbGemm = (n + 63) / 64;                // 1563

    hipMemsetAsync(gcnt, 0, (size_t)NB * 4, stream);
    k_fused<<<nbBin + nbGemm, 256, 0, stream>>>(row, col, gcnt, ebuf, E,
                                                x, W, yb, n, nbBin);
    k_cnt <<<NB, 256, 0, stream>>>(ebuf, gcnt, dinv, n);
    k_aggr<<<NB, 1024, 0, stream>>>(ebuf, gcnt, dinv, yb, bias, out, n);
}